// Round 11
// baseline (207.407 us; speedup 1.0000x reference)
//
#include <hip/hip_runtime.h>
#include <hip/hip_bf16.h>

constexpr int kB = 8, kN = 256, kD = 16, kHID = 256, kH = 128, kDH = 64, kdh = 32;
constexpr int kBN = kB * kN;          // 2048 rows
constexpr int kP  = kBN * kD;         // 32768 points

__device__ __forceinline__ float b2f(__hip_bfloat16 v) { return __bfloat162float(v); }
__device__ __forceinline__ __hip_bfloat16 f2b(float v) { return __float2bfloat16(v); }
__device__ __forceinline__ unsigned short f2bs(float v) {
    __hip_bfloat16 h = __float2bfloat16(v);
    return *(unsigned short*)&h;
}

__device__ __forceinline__ float tanh_fast(float v) {
    float e = __expf(2.f * v);
    return 1.f - 2.f * __builtin_amdgcn_rcpf(e + 1.f);
}

typedef short s8v  __attribute__((ext_vector_type(8)));   // 8 bf16 = 4 VGPRs
typedef float f4v  __attribute__((ext_vector_type(4)));
#define MFMA(a, b, c) __builtin_amdgcn_mfma_f32_16x16x32_bf16((a), (b), (c), 0, 0, 0)

// ---------- Prep: swizzle ALL weights into MFMA B-fragment layout (bf16) ----------
// Tile map (1840 tiles, 460 blocks x 4 tiles):
//   [0,64)      wcf  = p_w @ d_w0[2:]  (K=128,N=256) -- computed GEMM fold
//   [64,192)    w1f  (K=256,N=256)
//   [192,256)   w2f  (K=256,N=128)
//   [256,304)   k0f/v0f/q0f (K=16 pad 32, N=256; q masked)
//   [304,688)   k1f/v1f/q1f (K=256,N=256; q masked)
//   [688,816)   k2f/v2f (K=256,N=128)
//   [816,1840)  q2f (K=256,N=2048; masked)
__global__ __launch_bounds__(256) void prep_frag(
    const float* p_w, const float* d_w0, const float* d_w1, const float* d_w2,
    const float* k_w0, const float* k_w1, const float* k_w2,
    const float* v_w0, const float* v_w1, const float* v_w2,
    const float* q_w0, const float* q_w1, const float* q_w2,
    __hip_bfloat16* wcf, __hip_bfloat16* w1f, __hip_bfloat16* w2f,
    __hip_bfloat16* k0f, __hip_bfloat16* k1f, __hip_bfloat16* k2f,
    __hip_bfloat16* v0f, __hip_bfloat16* v1f, __hip_bfloat16* v2f,
    __hip_bfloat16* q0f, __hip_bfloat16* q1f, __hip_bfloat16* q2f)
{
    const int tile = blockIdx.x * 4 + (threadIdx.x >> 6);
    const int lane = threadIdx.x & 63;
    const int lx = lane & 15, quad = lane >> 4;

    if (tile < 64) {     // wcf: Wcomb[c][n] = sum_d p_w[c*64+d] * d_w0[(2+d)*256+n]
        const int kt = tile / 16, nt = tile % 16;
        const int col = nt * 16 + lx;
        __hip_bfloat16* o = wcf + ((size_t)tile * 64 + lane) * 8;
        #pragma unroll
        for (int j = 0; j < 8; ++j) {
            const int row = kt * 32 + quad * 8 + j;
            float s = 0.f;
            for (int d = 0; d < 64; ++d)
                s += p_w[row * 64 + d] * d_w0[(2 + d) * 256 + col];
            o[j] = f2b(s);
        }
        return;
    }

    const float* src; __hip_bfloat16* dst; int N, NT, local, Kreal = 1 << 30, mask = 0;
    if (tile < 192)       { src = d_w1; dst = w1f; N = 256;  NT = 16;  local = tile - 64; }
    else if (tile < 256)  { src = d_w2; dst = w2f; N = 128;  NT = 8;   local = tile - 192; }
    else if (tile < 272)  { src = k_w0; dst = k0f; N = 256;  NT = 16;  local = tile - 256; Kreal = 16; }
    else if (tile < 288)  { src = v_w0; dst = v0f; N = 256;  NT = 16;  local = tile - 272; Kreal = 16; }
    else if (tile < 304)  { src = q_w0; dst = q0f; N = 256;  NT = 16;  local = tile - 288; Kreal = 16; mask = 1; }
    else if (tile < 432)  { src = k_w1; dst = k1f; N = 256;  NT = 16;  local = tile - 304; }
    else if (tile < 560)  { src = v_w1; dst = v1f; N = 256;  NT = 16;  local = tile - 432; }
    else if (tile < 688)  { src = q_w1; dst = q1f; N = 256;  NT = 16;  local = tile - 560; mask = 2; }
    else if (tile < 752)  { src = k_w2; dst = k2f; N = 128;  NT = 8;   local = tile - 688; }
    else if (tile < 816)  { src = v_w2; dst = v2f; N = 128;  NT = 8;   local = tile - 752; }
    else                  { src = q_w2; dst = q2f; N = 2048; NT = 128; local = tile - 816; mask = 3; }
    const int kt = local / NT, nt = local % NT;
    const int row0 = kt * 32 + quad * 8;
    const int col  = nt * 16 + lx;
    __hip_bfloat16* o = dst + ((size_t)local * 64 + lane) * 8;
    #pragma unroll
    for (int j = 0; j < 8; ++j) {
        const int r = row0 + j;
        float w = (r < Kreal) ? src[(size_t)r * N + col] : 0.f;
        if (mask == 1 && !((col % 15) >= r))        w = 0.f;
        if (mask == 2 && !((col % 15) >= (r % 15))) w = 0.f;
        if (mask == 3 && !((col >> 7) > (r % 15)))  w = 0.f;
        o[j] = f2b(w);
    }
}

// bc0[n] = sum_d p_b[d] * d_w0[(2+d)*256+n]
__global__ __launch_bounds__(256) void prep_bias(
    const float* p_b, const float* d_w0, float* bc0)
{
    const int n = threadIdx.x;
    float s = 0.f;
    for (int d = 0; d < 64; ++d) s += p_b[d] * d_w0[(2 + d) * 256 + n];
    bc0[n] = s;
}

// ---------- Kernel 1: MFMA MLPs, one path per block. grid = 64 row-tiles x 3 paths ----------
__global__ __launch_bounds__(256) void mlp_kernel(
    const float* x,
    const float* k_b0, const float* k_b1, const float* k_b2,
    const float* v_b0, const float* v_b1, const float* v_b2,
    const float* q_b0, const float* q_b1,
    const __hip_bfloat16* k0f, const __hip_bfloat16* k1f, const __hip_bfloat16* k2f,
    const __hip_bfloat16* v0f, const __hip_bfloat16* v1f, const __hip_bfloat16* v2f,
    const __hip_bfloat16* q0f, const __hip_bfloat16* q1f,
    __hip_bfloat16* kbuf, __hip_bfloat16* vbuf, __hip_bfloat16* h1q)
{
    constexpr int SA = 264;
    constexpr int SX = 40;
    __shared__ __hip_bfloat16 xin[32 * SX];
    __shared__ __hip_bfloat16 bufA[32 * SA];
    __shared__ __hip_bfloat16 bufB[32 * SA];

    const int tid  = threadIdx.x;
    const int wv   = tid >> 6, lane = tid & 63;
    const int lx   = lane & 15, quad = lane >> 4;
    const int path = blockIdx.x >> 6;             // 0=k, 1=v, 2=q
    const int r0   = (blockIdx.x & 63) * 32;

    auto ldA = [&](const __hip_bfloat16* buf, int stride, int m0, int k0) -> s8v {
        return *(const s8v*)(buf + (m0 + lx) * stride + k0 + quad * 8);
    };
    auto ldB = [&](const __hip_bfloat16* wf, int NT, int kt, int nt) -> s8v {
        return *(const s8v*)(wf + (((size_t)(kt * NT + nt) * 64 + lane) << 3));
    };

    for (int idx = tid; idx < 1024; idx += 256) {
        const int row = idx >> 5, c = idx & 31;
        xin[row * SX + c] = f2b(c < 16 ? x[(r0 + row) * kD + c] : 0.f);
    }

    const __hip_bfloat16* F0[3] = { k0f, v0f, q0f };
    const __hip_bfloat16* F1[3] = { k1f, v1f, q1f };
    const __hip_bfloat16* F2[2] = { k2f, v2f };
    const float* Ba0[3] = { k_b0, v_b0, q_b0 };
    const float* Ba1[3] = { k_b1, v_b1, q_b1 };
    const float* Ba2[2] = { k_b2, v_b2 };
    __hip_bfloat16* O2[2] = { kbuf, vbuf };

    __syncthreads();

    {   // L0: M=32, N=256, K=32 (padded)
        f4v acc[4][2] = {};
        const s8v a0 = ldA(xin, SX, 0, 0);
        const s8v a1 = ldA(xin, SX, 16, 0);
        #pragma unroll
        for (int j = 0; j < 4; ++j) {
            s8v b = ldB(F0[path], 16, 0, wv * 4 + j);
            acc[j][0] = MFMA(a0, b, acc[j][0]);
            acc[j][1] = MFMA(a1, b, acc[j][1]);
        }
        #pragma unroll
        for (int j = 0; j < 4; ++j) {
            const int n = (wv * 4 + j) * 16 + lx;
            const float bb = Ba0[path][n];
            #pragma unroll
            for (int mt = 0; mt < 2; ++mt)
            #pragma unroll
            for (int r = 0; r < 4; ++r) {
                const float v = acc[j][mt][r] + bb;
                const float z = (path == 2) ? fmaxf(v, 0.f) : tanh_fast(v);
                bufA[(mt * 16 + quad * 4 + r) * SA + n] = f2b(z);
            }
        }
    }
    __syncthreads();

    {   // L1: M=32, N=256, K=256
        f4v acc[4][2] = {};
        #pragma unroll
        for (int kt = 0; kt < 8; ++kt) {
            const s8v a0 = ldA(bufA, SA, 0, kt * 32);
            const s8v a1 = ldA(bufA, SA, 16, kt * 32);
            #pragma unroll
            for (int j = 0; j < 4; ++j) {
                s8v b = ldB(F1[path], 16, kt, wv * 4 + j);
                acc[j][0] = MFMA(a0, b, acc[j][0]);
                acc[j][1] = MFMA(a1, b, acc[j][1]);
            }
        }
        #pragma unroll
        for (int j = 0; j < 4; ++j) {
            const int n = (wv * 4 + j) * 16 + lx;
            const float bb = Ba1[path][n];
            #pragma unroll
            for (int mt = 0; mt < 2; ++mt)
            #pragma unroll
            for (int r = 0; r < 4; ++r) {
                const int m = mt * 16 + quad * 4 + r;
                const float v = acc[j][mt][r] + bb;
                if (path == 2) {
                    h1q[(size_t)(r0 + m) * 256 + n] = f2b(fmaxf(v, 0.f));
                } else {
                    bufB[m * SA + n] = f2b(tanh_fast(v));
                }
            }
        }
    }
    if (path == 2) return;
    __syncthreads();

    {   // L2: M=32, N=128, K=256, linear -> kbuf/vbuf
        f4v acc[2][2] = {};
        #pragma unroll
        for (int kt = 0; kt < 8; ++kt) {
            const s8v a0 = ldA(bufB, SA, 0, kt * 32);
            const s8v a1 = ldA(bufB, SA, 16, kt * 32);
            #pragma unroll
            for (int j = 0; j < 2; ++j) {
                s8v b = ldB(F2[path], 8, kt, wv * 2 + j);
                acc[j][0] = MFMA(a0, b, acc[j][0]);
                acc[j][1] = MFMA(a1, b, acc[j][1]);
            }
        }
        #pragma unroll
        for (int j = 0; j < 2; ++j) {
            const int n = (wv * 2 + j) * 16 + lx;
            const float bb = Ba2[path][n];
            #pragma unroll
            for (int mt = 0; mt < 2; ++mt)
            #pragma unroll
            for (int r = 0; r < 4; ++r) {
                const int m = mt * 16 + quad * 4 + r;
                O2[path][(size_t)(r0 + m) * kH + n] = f2b(acc[j][mt][r] + bb);
            }
        }
    }
}

// ---------- Kernel 2: q layer-2 GEMM: M=2048, N=2048, K=256. Scale folded into output. ----------
__global__ __launch_bounds__(256) void qgemm_kernel(
    const float* q_b2, const __hip_bfloat16* h1q, const __hip_bfloat16* q2f,
    __hip_bfloat16* qbuf)
{
    constexpr int SA = 264;
    __shared__ __hip_bfloat16 hin[32 * SA];

    const int tid  = threadIdx.x;
    const int wv   = tid >> 6, lane = tid & 63;
    const int lx   = lane & 15, quad = lane >> 4;
    const int ct   = blockIdx.x & 7;
    const int r0   = (blockIdx.x >> 3) * 32;

    for (int idx = tid; idx < 1024; idx += 256) {
        const int row = idx >> 5, seg = idx & 31;
        *(f4v*)(hin + row * SA + seg * 8) = *(const f4v*)(h1q + (size_t)(r0 + row) * 256 + seg * 8);
    }
    __syncthreads();

    f4v acc[4][2] = {};
    #pragma unroll
    for (int kt = 0; kt < 8; ++kt) {
        const s8v a0 = *(const s8v*)(hin + lx * SA + kt * 32 + quad * 8);
        const s8v a1 = *(const s8v*)(hin + (16 + lx) * SA + kt * 32 + quad * 8);
        #pragma unroll
        for (int j = 0; j < 4; ++j) {
            s8v b = *(const s8v*)(q2f + (((size_t)(kt * 128 + ct * 16 + wv * 4 + j) * 64 + lane) << 3));
            acc[j][0] = MFMA(a0, b, acc[j][0]);
            acc[j][1] = MFMA(a1, b, acc[j][1]);
        }
    }
    const float scale = 0.17677669529663687f;     // 1/sqrt(32)
    #pragma unroll
    for (int j = 0; j < 4; ++j) {
        const int col = ct * 256 + (wv * 4 + j) * 16 + lx;
        const float bb = q_b2[col];
        #pragma unroll
        for (int mt = 0; mt < 2; ++mt)
        #pragma unroll
        for (int r = 0; r < 4; ++r) {
            const int row = r0 + mt * 16 + quad * 4 + r;
            qbuf[(size_t)row * 2048 + col] = f2b((acc[j][mt][r] + bb) * scale);
        }
    }
}

// ---------- Kernel 3: MFMA attention. 4 waves/block (wave = 64-query group) ----------
__global__ __launch_bounds__(256, 2) void attn_kernel(
    const __hip_bfloat16* qbuf, const __hip_bfloat16* kbuf, const __hip_bfloat16* vbuf,
    __hip_bfloat16* obuf)
{
    constexpr int SP = 264;
    __shared__ short Pl[4][16 * SP];

    const int blk = blockIdx.x;                   // b*64 + d*4 + hd
    const int hd = blk & 3;
    const int d  = (blk >> 2) & 15;
    const int b  = blk >> 6;

    const int wv   = threadIdx.x >> 6;            // query group
    const int lane = threadIdx.x & 63;
    const int lx = lane & 15, quad = lane >> 4;
    short* Pw = &Pl[wv][0];

    const short* kb = (const short*)kbuf;
    const short* vb = (const short*)vbuf;
    const short* qb = (const short*)qbuf;

    s8v kfrag[16];
    #pragma unroll
    for (int mt = 0; mt < 16; ++mt)
        kfrag[mt] = *(const s8v*)(kb + (size_t)(b * 256 + mt * 16 + lx) * 128 + hd * 32 + quad * 8);

    s8v vfrag[2][8];
    #pragma unroll
    for (int ntv = 0; ntv < 2; ++ntv)
    #pragma unroll
    for (int kt = 0; kt < 8; ++kt) {
        s8v v;
        #pragma unroll
        for (int j = 0; j < 8; ++j)
            v[j] = vb[(size_t)(b * 256 + kt * 32 + quad * 8 + j) * 128 + hd * 32 + ntv * 16 + lx];
        vfrag[ntv][kt] = v;
    }

    const float LOG2E = 1.4426950408889634f;

    for (int mi = 0; mi < 4; ++mi) {
        const int q0 = wv * 64 + mi * 16;

        s8v qfrag = *(const s8v*)(qb + (size_t)(b * 256 + q0 + lx) * 2048 + d * 128 + hd * 32 + quad * 8);

        f4v acc[16];
        #pragma unroll
        for (int mt = 0; mt < 16; ++mt) acc[mt] = f4v{0.f, 0.f, 0.f, 0.f};
        #pragma unroll
        for (int mt = 0; mt < 16; ++mt) acc[mt] = MFMA(kfrag[mt], qfrag, acc[mt]);

        const int qg = q0 + lx;
        float mx = -3.0e38f;
        #pragma unroll
        for (int mt = 0; mt < 16; ++mt)
        #pragma unroll
        for (int r = 0; r < 4; ++r) {
            const int key = mt * 16 + quad * 4 + r;
            float s = (key == qg) ? -3.0e38f : acc[mt][r];
            acc[mt][r] = s;
            mx = fmaxf(mx, s);
        }
        mx = fmaxf(mx, __shfl_xor(mx, 16, 64));
        mx = fmaxf(mx, __shfl_xor(mx, 32, 64));

        const float nmxc = -mx * LOG2E;
        float l = 0.f;
        #pragma unroll
        for (int mt = 0; mt < 16; ++mt)
        #pragma unroll
        for (int r = 0; r < 4; ++r) {
            float p = exp2f(__builtin_fmaf(acc[mt][r], LOG2E, nmxc));
            acc[mt][r] = p;
            l += p;
        }
        l += __shfl_xor(l, 16, 64);
        l += __shfl_xor(l, 32, 64);

        #pragma unroll
        for (int mt = 0; mt < 16; ++mt) {
            unsigned short h0 = f2bs(acc[mt][0]);
            unsigned short h1 = f2bs(acc[mt][1]);
            unsigned short h2 = f2bs(acc[mt][2]);
            unsigned short h3 = f2bs(acc[mt][3]);
            uint2 w;
            w.x = (unsigned int)h0 | ((unsigned int)h1 << 16);
            w.y = (unsigned int)h2 | ((unsigned int)h3 << 16);
            *(uint2*)(Pw + lx * SP + mt * 16 + quad * 4) = w;
        }
        __asm__ volatile("s_waitcnt lgkmcnt(0)" ::: "memory");

        f4v av[2] = { f4v{0.f,0.f,0.f,0.f}, f4v{0.f,0.f,0.f,0.f} };
        #pragma unroll
        for (int kt = 0; kt < 8; ++kt) {
            s8v a = *(const s8v*)(Pw + lx * SP + kt * 32 + quad * 8);
            av[0] = MFMA(a, vfrag[0][kt], av[0]);
            av[1] = MFMA(a, vfrag[1][kt], av[1]);
        }
        __asm__ volatile("s_waitcnt lgkmcnt(0)" ::: "memory");

        #pragma unroll
        for (int r = 0; r < 4; ++r) {
            const float lr = __shfl(l, quad * 4 + r, 64);
            const float inv = __builtin_amdgcn_rcpf(lr);
            const int qrow = q0 + quad * 4 + r;
            #pragma unroll
            for (int ntv = 0; ntv < 2; ++ntv) {
                obuf[((size_t)((b * 256 + qrow) * 16 + d)) * 128 + hd * 32 + ntv * 16 + lx]
                    = f2b(av[ntv][r] * inv);
            }
        }
    }
}

// ---------- Kernel 4: MFMA dimwise net. 16 pts/block, 8 waves (512 thr), folded proj, 32 waves/CU ----------
__global__ __launch_bounds__(512) void dim_kernel(
    const float* t, const float* x,
    const float* d_w0, const float* d_b0, const float* bc0,
    const float* d_b1, const float* d_b2, const float* d_w3, const float* d_b3,
    const __hip_bfloat16* wcf, const __hip_bfloat16* w1f, const __hip_bfloat16* w2f,
    const __hip_bfloat16* obuf, float* out)
{
    constexpr int SA = 264;
    constexpr int SO = 136;
    __shared__ __hip_bfloat16 bufA[32 * SA];   // 16.9 KB
    __shared__ __hip_bfloat16 bufB[32 * SA];   // 16.9 KB
    __shared__ float xvs[16];

    const int tid  = threadIdx.x;
    const int wv   = tid >> 6, lane = tid & 63;   // wv in [0,8)
    const int lx   = lane & 15, quad = lane >> 4;
    const int p0   = blockIdx.x * 16;
    const float tval = t[0];

    auto ldA = [&](const __hip_bfloat16* buf, int stride, int m0, int k0) -> s8v {
        return *(const s8v*)(buf + (m0 + lx) * stride + k0 + quad * 8);
    };
    auto ldBf = [&](const __hip_bfloat16* wf, int NT, int kt, int nt) -> s8v {
        return *(const s8v*)(wf + (((size_t)(kt * NT + nt) * 64 + lane) << 3));
    };

    // stage obuf rows (16 x 128) -> bufA stride SO
    if (tid < 256) {
        const int row = tid >> 4, ch = tid & 15;
        *(f4v*)(bufA + row * SO + ch * 8) = *(const f4v*)(obuf + (size_t)(p0 + row) * kH + ch * 8);
    }
    if (tid < 16) xvs[tid] = x[p0 + tid];
    __syncthreads();

    {   // L0 (folded): M=16, N=256, K=128. read bufA -> write bufB (z rows 0-15, zd 16-31)
        f4v acc[2] = {};
        #pragma unroll
        for (int ktile = 0; ktile < 4; ++ktile) {
            s8v a0 = ldA(bufA, SO, 0, ktile * 32);
            #pragma unroll
            for (int j = 0; j < 2; ++j) {
                s8v b = ldBf(wcf, 16, ktile, wv * 2 + j);
                acc[j] = MFMA(a0, b, acc[j]);
            }
        }
        #pragma unroll
        for (int j = 0; j < 2; ++j) {
            const int n = (wv * 2 + j) * 16 + lx;
            const float base = bc0[n] + d_b0[n] + tval * d_w0[n];
            const float wx   = d_w0[256 + n];
            #pragma unroll
            for (int r = 0; r < 4; ++r) {
                const int m = quad * 4 + r;
                const float z = tanh_fast(acc[j][r] + base + xvs[m] * wx);
                bufB[m * SA + n]        = f2b(z);
                bufB[(m + 16) * SA + n] = f2b((1.f - z * z) * wx);
            }
        }
    }
    __syncthreads();

    {   // L1: M=32 (16 fwd + 16 tgt), N=256, K=256. read bufB -> write bufA
        f4v acc[2][2] = {};
        #pragma unroll
        for (int ktile = 0; ktile < 8; ++ktile) {
            s8v a0 = ldA(bufB, SA, 0,  ktile * 32);
            s8v a1 = ldA(bufB, SA, 16, ktile * 32);
            #pragma unroll
            for (int j = 0; j < 2; ++j) {
                s8v b = ldBf(w1f, 16, ktile, wv * 2 + j);
                acc[j][0] = MFMA(a0, b, acc[j][0]);
                acc[j][1] = MFMA(a1, b, acc[j][1]);
            }
        }
        #pragma unroll
        for (int j = 0; j < 2; ++j) {
            const int n = (wv * 2 + j) * 16 + lx;
            const float b1 = d_b1[n];
            #pragma unroll
            for (int r = 0; r < 4; ++r) {
                const int m = quad * 4 + r;
                const float z  = tanh_fast(acc[j][0][r] + b1);
                const float zd = (1.f - z * z) * acc[j][1][r];
                bufA[m * SA + n]        = f2b(z);
                bufA[(m + 16) * SA + n] = f2b(zd);
            }
        }
    }
    __syncthreads();

    {   // L2: M=32, N=128, K=256. read bufA -> write bufB (stride SO). wave -> 1 n-tile
        f4v acc[2] = {};
        #pragma unroll
        for (int ktile = 0; ktile < 8; ++ktile) {
            s8v a0 = ldA(bufA, SA, 0,  ktile * 32);
            s8v a1 = ldA(bufA, SA, 16, ktile * 32);
            s8v b = ldBf(w2f, 8, ktile, wv);
            acc[0] = MFMA(a0, b, acc[0]);
            acc[1] = MFMA(a1, b, acc[1]);
        }
        const int n = wv * 16 + lx;
        const float b2 = d_b2[n];
        #pragma unroll
        for (int r = 0; r < 4; ++r) {
            const int m = quad * 4 + r;
            const float z  = tanh_fast(acc[0][r] + b2);
            const float zd = (1.f - z * z) * acc[1][r];
            bufB[m * SO + n]        = f2b(z);
            bufB[(m + 16) * SO + n] = f2b(zd);
        }
    }
    __syncthreads();

    {   // L3 reduce: 16 points x 32 threads, 4 cols each
        const int p = tid >> 5, s = tid & 31;
        float yv = 0.f, jv = 0.f;
        #pragma unroll
        for (int i = 0; i < 4; ++i) {
            const int n = s + i * 32;
            const float w = d_w3[n];
            yv += b2f(bufB[p * SO + n]) * w;
            jv += b2f(bufB[(p + 16) * SO + n]) * w;
        }
        #pragma unroll
        for (int off = 16; off > 0; off >>= 1) {
            yv += __shfl_down(yv, off, 32);
            jv += __shfl_down(jv, off, 32);
        }
        if (s == 0) {
            out[p0 + p]      = yv + d_b3[0];
            out[kP + p0 + p] = jv;
        }
    }
}

extern "C" void kernel_launch(void* const* d_in, const int* in_sizes, int n_in,
                              void* d_out, int out_size, void* d_ws, size_t ws_size,
                              hipStream_t stream)
{
    typedef const float* fp;
    fp t    = (fp)d_in[0];
    fp x    = (fp)d_in[1];
    fp q_w0 = (fp)d_in[2],  q_b0 = (fp)d_in[3];
    fp k_w0 = (fp)d_in[4],  k_b0 = (fp)d_in[5];
    fp v_w0 = (fp)d_in[6],  v_b0 = (fp)d_in[7];
    fp q_w1 = (fp)d_in[8],  q_b1 = (fp)d_in[9];
    fp k_w1 = (fp)d_in[10], k_b1 = (fp)d_in[11];
    fp v_w1 = (fp)d_in[12], v_b1 = (fp)d_in[13];
    fp q_w2 = (fp)d_in[14], q_b2 = (fp)d_in[15];
    fp k_w2 = (fp)d_in[16], k_b2 = (fp)d_in[17];
    fp v_w2 = (fp)d_in[18], v_b2 = (fp)d_in[19];
    fp p_w  = (fp)d_in[20], p_b  = (fp)d_in[21];
    fp d_w0 = (fp)d_in[22], d_b0 = (fp)d_in[23];
    fp d_w1 = (fp)d_in[24], d_b1 = (fp)d_in[25];
    fp d_w2 = (fp)d_in[26], d_b2 = (fp)d_in[27];
    fp d_w3 = (fp)d_in[28], d_b3 = (fp)d_in[29];

    __hip_bfloat16* wsb  = (__hip_bfloat16*)d_ws;
    __hip_bfloat16* kbuf = wsb;                                  // 2048*128
    __hip_bfloat16* vbuf = kbuf + (size_t)kBN * kH;              // 2048*128
    __hip_bfloat16* qbuf = vbuf + (size_t)kBN * kH;              // 2048*2048
    __hip_bfloat16* obuf = qbuf + (size_t)kBN * kD * kH;         // 32768*128
    __hip_bfloat16* wcf  = obuf + (size_t)kP * kH;               // 32768 (128x256)
    __hip_bfloat16* w1f  = wcf + 32768;                          // 65536
    __hip_bfloat16* w2f  = w1f + 65536;                          // 32768
    __hip_bfloat16* k0f  = w2f + 32768;                          // 8192
    __hip_bfloat16* v0f  = k0f + 8192;                           // 8192
    __hip_bfloat16* q0f  = v0f + 8192;                           // 8192
    __hip_bfloat16* k1f  = q0f + 8192;                           // 65536
    __hip_bfloat16* v1f  = k1f + 65536;                          // 65536
    __hip_bfloat16* q1f  = v1f + 65536;                          // 65536
    __hip_bfloat16* k2f  = q1f + 65536;                          // 32768
    __hip_bfloat16* v2f  = k2f + 32768;                          // 32768
    __hip_bfloat16* q2f  = v2f + 32768;                          // 524288
    __hip_bfloat16* h1q  = q2f + 524288;                         // 524288
    float* bc0 = (float*)(h1q + 524288);                         // 256 fp32

    float* out = (float*)d_out;

    prep_frag<<<460, 256, 0, stream>>>(p_w, d_w0, d_w1, d_w2,
        k_w0, k_w1, k_w2, v_w0, v_w1, v_w2, q_w0, q_w1, q_w2,
        wcf, w1f, w2f, k0f, k1f, k2f, v0f, v1f, v2f, q0f, q1f, q2f);
    prep_bias<<<1, 256, 0, stream>>>(p_b, d_w0, bc0);
    mlp_kernel<<<192, 256, 0, stream>>>(x,
        k_b0, k_b1, k_b2, v_b0, v_b1, v_b2, q_b0, q_b1,
        k0f, k1f, k2f, v0f, v1f, v2f, q0f, q1f, kbuf, vbuf, h1q);
    qgemm_kernel<<<(kBN / 32) * 8, 256, 0, stream>>>(q_b2, h1q, q2f, qbuf);
    attn_kernel<<<kB * kD * 4, 256, 0, stream>>>(qbuf, kbuf, vbuf, obuf);
    dim_kernel<<<kP / 16, 512, 0, stream>>>(t, x, d_w0, d_b0, bc0,
        d_b1, d_b2, d_w3, d_b3, wcf, w1f, w2f, obuf, out);
}

// Round 12
// 193.560 us; speedup vs baseline: 1.0715x; 1.0715x over previous
//
#include <hip/hip_runtime.h>
#include <hip/hip_bf16.h>

constexpr int kB = 8, kN = 256, kD = 16, kHID = 256, kH = 128, kDH = 64, kdh = 32;
constexpr int kBN = kB * kN;          // 2048 rows
constexpr int kP  = kBN * kD;         // 32768 points

__device__ __forceinline__ float b2f(__hip_bfloat16 v) { return __bfloat162float(v); }
__device__ __forceinline__ __hip_bfloat16 f2b(float v) { return __float2bfloat16(v); }
__device__ __forceinline__ unsigned short f2bs(float v) {
    __hip_bfloat16 h = __float2bfloat16(v);
    return *(unsigned short*)&h;
}

__device__ __forceinline__ float tanh_fast(float v) {
    float e = __expf(2.f * v);
    return 1.f - 2.f * __builtin_amdgcn_rcpf(e + 1.f);
}

typedef short s8v  __attribute__((ext_vector_type(8)));   // 8 bf16 = 4 VGPRs
typedef float f4v  __attribute__((ext_vector_type(4)));
#define MFMA(a, b, c) __builtin_amdgcn_mfma_f32_16x16x32_bf16((a), (b), (c), 0, 0, 0)

// ---------- Prep: swizzle ALL weights into MFMA B-fragment layout (bf16) ----------
__global__ __launch_bounds__(256) void prep_frag(
    const float* p_w, const float* d_w0, const float* d_w1, const float* d_w2,
    const float* k_w0, const float* k_w1, const float* k_w2,
    const float* v_w0, const float* v_w1, const float* v_w2,
    const float* q_w0, const float* q_w1, const float* q_w2,
    __hip_bfloat16* pwf, __hip_bfloat16* w0f, __hip_bfloat16* w1f, __hip_bfloat16* w2f,
    __hip_bfloat16* k0f, __hip_bfloat16* k1f, __hip_bfloat16* k2f,
    __hip_bfloat16* v0f, __hip_bfloat16* v1f, __hip_bfloat16* v2f,
    __hip_bfloat16* q0f, __hip_bfloat16* q1f, __hip_bfloat16* q2f)
{
    const int tile = blockIdx.x * 4 + (threadIdx.x >> 6);
    const int lane = threadIdx.x & 63;
    const float* src; __hip_bfloat16* dst; int N, NT, local, Kreal = 1 << 30, mask = 0;
    if (tile < 16)        { src = p_w;        dst = pwf; N = 64;   NT = 4;   local = tile; }
    else if (tile < 48)   { src = d_w0 + 512; dst = w0f; N = 256;  NT = 16;  local = tile - 16; }
    else if (tile < 176)  { src = d_w1;       dst = w1f; N = 256;  NT = 16;  local = tile - 48; }
    else if (tile < 240)  { src = d_w2;       dst = w2f; N = 128;  NT = 8;   local = tile - 176; }
    else if (tile < 256)  { src = k_w0;       dst = k0f; N = 256;  NT = 16;  local = tile - 240; Kreal = 16; }
    else if (tile < 272)  { src = v_w0;       dst = v0f; N = 256;  NT = 16;  local = tile - 256; Kreal = 16; }
    else if (tile < 288)  { src = q_w0;       dst = q0f; N = 256;  NT = 16;  local = tile - 272; Kreal = 16; mask = 1; }
    else if (tile < 416)  { src = k_w1;       dst = k1f; N = 256;  NT = 16;  local = tile - 288; }
    else if (tile < 544)  { src = v_w1;       dst = v1f; N = 256;  NT = 16;  local = tile - 416; }
    else if (tile < 672)  { src = q_w1;       dst = q1f; N = 256;  NT = 16;  local = tile - 544; mask = 2; }
    else if (tile < 736)  { src = k_w2;       dst = k2f; N = 128;  NT = 8;   local = tile - 672; }
    else if (tile < 800)  { src = v_w2;       dst = v2f; N = 128;  NT = 8;   local = tile - 736; }
    else                  { src = q_w2;       dst = q2f; N = 2048; NT = 128; local = tile - 800; mask = 3; }
    const int kt = local / NT, nt = local % NT;
    const int row0 = kt * 32 + (lane >> 4) * 8;
    const int col  = nt * 16 + (lane & 15);
    __hip_bfloat16* o = dst + ((size_t)local * 64 + lane) * 8;
    #pragma unroll
    for (int j = 0; j < 8; ++j) {
        const int r = row0 + j;
        float w = (r < Kreal) ? src[(size_t)r * N + col] : 0.f;
        if (mask == 1 && !((col % 15) >= r))        w = 0.f;
        if (mask == 2 && !((col % 15) >= (r % 15))) w = 0.f;
        if (mask == 3 && !((col >> 7) > (r % 15)))  w = 0.f;
        o[j] = f2b(w);
    }
}

// ---------- Kernel 1: MFMA MLPs, one path per block. grid = 64 row-tiles x 3 paths ----------
__global__ __launch_bounds__(256) void mlp_kernel(
    const float* x,
    const float* k_b0, const float* k_b1, const float* k_b2,
    const float* v_b0, const float* v_b1, const float* v_b2,
    const float* q_b0, const float* q_b1,
    const __hip_bfloat16* k0f, const __hip_bfloat16* k1f, const __hip_bfloat16* k2f,
    const __hip_bfloat16* v0f, const __hip_bfloat16* v1f, const __hip_bfloat16* v2f,
    const __hip_bfloat16* q0f, const __hip_bfloat16* q1f,
    __hip_bfloat16* kbuf, __hip_bfloat16* vbuf, __hip_bfloat16* h1q)
{
    constexpr int SA = 264;
    constexpr int SX = 40;
    __shared__ __hip_bfloat16 xin[32 * SX];
    __shared__ __hip_bfloat16 bufA[32 * SA];
    __shared__ __hip_bfloat16 bufB[32 * SA];

    const int tid  = threadIdx.x;
    const int wv   = tid >> 6, lane = tid & 63;
    const int lx   = lane & 15, quad = lane >> 4;
    const int path = blockIdx.x >> 6;             // 0=k, 1=v, 2=q
    const int r0   = (blockIdx.x & 63) * 32;

    auto ldA = [&](const __hip_bfloat16* buf, int stride, int m0, int k0) -> s8v {
        return *(const s8v*)(buf + (m0 + lx) * stride + k0 + quad * 8);
    };
    auto ldB = [&](const __hip_bfloat16* wf, int NT, int kt, int nt) -> s8v {
        return *(const s8v*)(wf + (((size_t)(kt * NT + nt) * 64 + lane) << 3));
    };

    for (int idx = tid; idx < 1024; idx += 256) {
        const int row = idx >> 5, c = idx & 31;
        xin[row * SX + c] = f2b(c < 16 ? x[(r0 + row) * kD + c] : 0.f);
    }

    const __hip_bfloat16* F0[3] = { k0f, v0f, q0f };
    const __hip_bfloat16* F1[3] = { k1f, v1f, q1f };
    const __hip_bfloat16* F2[2] = { k2f, v2f };
    const float* Ba0[3] = { k_b0, v_b0, q_b0 };
    const float* Ba1[3] = { k_b1, v_b1, q_b1 };
    const float* Ba2[2] = { k_b2, v_b2 };
    __hip_bfloat16* O2[2] = { kbuf, vbuf };

    __syncthreads();

    {   // L0: M=32, N=256, K=32 (padded)
        f4v acc[4][2] = {};
        const s8v a0 = ldA(xin, SX, 0, 0);
        const s8v a1 = ldA(xin, SX, 16, 0);
        #pragma unroll
        for (int j = 0; j < 4; ++j) {
            s8v b = ldB(F0[path], 16, 0, wv * 4 + j);
            acc[j][0] = MFMA(a0, b, acc[j][0]);
            acc[j][1] = MFMA(a1, b, acc[j][1]);
        }
        #pragma unroll
        for (int j = 0; j < 4; ++j) {
            const int n = (wv * 4 + j) * 16 + lx;
            const float bb = Ba0[path][n];
            #pragma unroll
            for (int mt = 0; mt < 2; ++mt)
            #pragma unroll
            for (int r = 0; r < 4; ++r) {
                const float v = acc[j][mt][r] + bb;
                const float z = (path == 2) ? fmaxf(v, 0.f) : tanh_fast(v);
                bufA[(mt * 16 + quad * 4 + r) * SA + n] = f2b(z);
            }
        }
    }
    __syncthreads();

    {   // L1: M=32, N=256, K=256
        f4v acc[4][2] = {};
        #pragma unroll
        for (int kt = 0; kt < 8; ++kt) {
            const s8v a0 = ldA(bufA, SA, 0, kt * 32);
            const s8v a1 = ldA(bufA, SA, 16, kt * 32);
            #pragma unroll
            for (int j = 0; j < 4; ++j) {
                s8v b = ldB(F1[path], 16, kt, wv * 4 + j);
                acc[j][0] = MFMA(a0, b, acc[j][0]);
                acc[j][1] = MFMA(a1, b, acc[j][1]);
            }
        }
        #pragma unroll
        for (int j = 0; j < 4; ++j) {
            const int n = (wv * 4 + j) * 16 + lx;
            const float bb = Ba1[path][n];
            #pragma unroll
            for (int mt = 0; mt < 2; ++mt)
            #pragma unroll
            for (int r = 0; r < 4; ++r) {
                const int m = mt * 16 + quad * 4 + r;
                const float v = acc[j][mt][r] + bb;
                if (path == 2) {
                    h1q[(size_t)(r0 + m) * 256 + n] = f2b(fmaxf(v, 0.f));
                } else {
                    bufB[m * SA + n] = f2b(tanh_fast(v));
                }
            }
        }
    }
    if (path == 2) return;
    __syncthreads();

    {   // L2: M=32, N=128, K=256, linear -> kbuf/vbuf
        f4v acc[2][2] = {};
        #pragma unroll
        for (int kt = 0; kt < 8; ++kt) {
            const s8v a0 = ldA(bufB, SA, 0, kt * 32);
            const s8v a1 = ldA(bufB, SA, 16, kt * 32);
            #pragma unroll
            for (int j = 0; j < 2; ++j) {
                s8v b = ldB(F2[path], 8, kt, wv * 2 + j);
                acc[j][0] = MFMA(a0, b, acc[j][0]);
                acc[j][1] = MFMA(a1, b, acc[j][1]);
            }
        }
        #pragma unroll
        for (int j = 0; j < 2; ++j) {
            const int n = (wv * 2 + j) * 16 + lx;
            const float bb = Ba2[path][n];
            #pragma unroll
            for (int mt = 0; mt < 2; ++mt)
            #pragma unroll
            for (int r = 0; r < 4; ++r) {
                const int m = mt * 16 + quad * 4 + r;
                O2[path][(size_t)(r0 + m) * kH + n] = f2b(acc[j][mt][r] + bb);
            }
        }
    }
}

// ---------- Kernel 2: q layer-2 GEMM: M=2048, N=2048, K=256. Scale folded into output. ----------
__global__ __launch_bounds__(256) void qgemm_kernel(
    const float* q_b2, const __hip_bfloat16* h1q, const __hip_bfloat16* q2f,
    __hip_bfloat16* qbuf)
{
    constexpr int SA = 264;
    __shared__ __hip_bfloat16 hin[32 * SA];

    const int tid  = threadIdx.x;
    const int wv   = tid >> 6, lane = tid & 63;
    const int lx   = lane & 15, quad = lane >> 4;
    const int ct   = blockIdx.x & 7;
    const int r0   = (blockIdx.x >> 3) * 32;

    for (int idx = tid; idx < 1024; idx += 256) {
        const int row = idx >> 5, seg = idx & 31;
        *(f4v*)(hin + row * SA + seg * 8) = *(const f4v*)(h1q + (size_t)(r0 + row) * 256 + seg * 8);
    }
    __syncthreads();

    f4v acc[4][2] = {};
    #pragma unroll
    for (int kt = 0; kt < 8; ++kt) {
        const s8v a0 = *(const s8v*)(hin + lx * SA + kt * 32 + quad * 8);
        const s8v a1 = *(const s8v*)(hin + (16 + lx) * SA + kt * 32 + quad * 8);
        #pragma unroll
        for (int j = 0; j < 4; ++j) {
            s8v b = *(const s8v*)(q2f + (((size_t)(kt * 128 + ct * 16 + wv * 4 + j) * 64 + lane) << 3));
            acc[j][0] = MFMA(a0, b, acc[j][0]);
            acc[j][1] = MFMA(a1, b, acc[j][1]);
        }
    }
    const float scale = 0.17677669529663687f;     // 1/sqrt(32)
    #pragma unroll
    for (int j = 0; j < 4; ++j) {
        const int col = ct * 256 + (wv * 4 + j) * 16 + lx;
        const float bb = q_b2[col];
        #pragma unroll
        for (int mt = 0; mt < 2; ++mt)
        #pragma unroll
        for (int r = 0; r < 4; ++r) {
            const int row = r0 + mt * 16 + quad * 4 + r;
            qbuf[(size_t)row * 2048 + col] = f2b((acc[j][mt][r] + bb) * scale);
        }
    }
}

// ---------- Kernel 3: MFMA attention. 4 waves/block (wave = 64-query group) ----------
__global__ __launch_bounds__(256, 2) void attn_kernel(
    const __hip_bfloat16* qbuf, const __hip_bfloat16* kbuf, const __hip_bfloat16* vbuf,
    __hip_bfloat16* obuf)
{
    constexpr int SP = 264;
    __shared__ short Pl[4][16 * SP];

    const int blk = blockIdx.x;                   // b*64 + d*4 + hd
    const int hd = blk & 3;
    const int d  = (blk >> 2) & 15;
    const int b  = blk >> 6;

    const int wv   = threadIdx.x >> 6;            // query group
    const int lane = threadIdx.x & 63;
    const int lx = lane & 15, quad = lane >> 4;
    short* Pw = &Pl[wv][0];

    const short* kb = (const short*)kbuf;
    const short* vb = (const short*)vbuf;
    const short* qb = (const short*)qbuf;

    s8v kfrag[16];
    #pragma unroll
    for (int mt = 0; mt < 16; ++mt)
        kfrag[mt] = *(const s8v*)(kb + (size_t)(b * 256 + mt * 16 + lx) * 128 + hd * 32 + quad * 8);

    s8v vfrag[2][8];
    #pragma unroll
    for (int ntv = 0; ntv < 2; ++ntv)
    #pragma unroll
    for (int kt = 0; kt < 8; ++kt) {
        s8v v;
        #pragma unroll
        for (int j = 0; j < 8; ++j)
            v[j] = vb[(size_t)(b * 256 + kt * 32 + quad * 8 + j) * 128 + hd * 32 + ntv * 16 + lx];
        vfrag[ntv][kt] = v;
    }

    const float LOG2E = 1.4426950408889634f;

    for (int mi = 0; mi < 4; ++mi) {
        const int q0 = wv * 64 + mi * 16;

        s8v qfrag = *(const s8v*)(qb + (size_t)(b * 256 + q0 + lx) * 2048 + d * 128 + hd * 32 + quad * 8);

        f4v acc[16];
        #pragma unroll
        for (int mt = 0; mt < 16; ++mt) acc[mt] = f4v{0.f, 0.f, 0.f, 0.f};
        #pragma unroll
        for (int mt = 0; mt < 16; ++mt) acc[mt] = MFMA(kfrag[mt], qfrag, acc[mt]);

        const int qg = q0 + lx;
        float mx = -3.0e38f;
        #pragma unroll
        for (int mt = 0; mt < 16; ++mt)
        #pragma unroll
        for (int r = 0; r < 4; ++r) {
            const int key = mt * 16 + quad * 4 + r;
            float s = (key == qg) ? -3.0e38f : acc[mt][r];
            acc[mt][r] = s;
            mx = fmaxf(mx, s);
        }
        mx = fmaxf(mx, __shfl_xor(mx, 16, 64));
        mx = fmaxf(mx, __shfl_xor(mx, 32, 64));

        const float nmxc = -mx * LOG2E;
        float l = 0.f;
        #pragma unroll
        for (int mt = 0; mt < 16; ++mt)
        #pragma unroll
        for (int r = 0; r < 4; ++r) {
            float p = exp2f(__builtin_fmaf(acc[mt][r], LOG2E, nmxc));
            acc[mt][r] = p;
            l += p;
        }
        l += __shfl_xor(l, 16, 64);
        l += __shfl_xor(l, 32, 64);

        #pragma unroll
        for (int mt = 0; mt < 16; ++mt) {
            unsigned short h0 = f2bs(acc[mt][0]);
            unsigned short h1 = f2bs(acc[mt][1]);
            unsigned short h2 = f2bs(acc[mt][2]);
            unsigned short h3 = f2bs(acc[mt][3]);
            uint2 w;
            w.x = (unsigned int)h0 | ((unsigned int)h1 << 16);
            w.y = (unsigned int)h2 | ((unsigned int)h3 << 16);
            *(uint2*)(Pw + lx * SP + mt * 16 + quad * 4) = w;
        }
        __asm__ volatile("s_waitcnt lgkmcnt(0)" ::: "memory");

        f4v av[2] = { f4v{0.f,0.f,0.f,0.f}, f4v{0.f,0.f,0.f,0.f} };
        #pragma unroll
        for (int kt = 0; kt < 8; ++kt) {
            s8v a = *(const s8v*)(Pw + lx * SP + kt * 32 + quad * 8);
            av[0] = MFMA(a, vfrag[0][kt], av[0]);
            av[1] = MFMA(a, vfrag[1][kt], av[1]);
        }
        __asm__ volatile("s_waitcnt lgkmcnt(0)" ::: "memory");

        #pragma unroll
        for (int r = 0; r < 4; ++r) {
            const float lr = __shfl(l, quad * 4 + r, 64);
            const float inv = __builtin_amdgcn_rcpf(lr);
            const int qrow = q0 + quad * 4 + r;
            #pragma unroll
            for (int ntv = 0; ntv < 2; ++ntv) {
                obuf[((size_t)((b * 256 + qrow) * 16 + d)) * 128 + hd * 32 + ntv * 16 + lx]
                    = f2b(av[ntv][r] * inv);
            }
        }
    }
}

// ---------- Kernel 4: MFMA dimwise net. 16 points/block, dbuf pipeline, 4 blocks/CU ----------
__global__ __launch_bounds__(256) void dim_kernel(
    const float* t, const float* x,
    const float* p_b, const float* d_w0, const float* d_b0,
    const float* d_b1, const float* d_b2, const float* d_w3, const float* d_b3,
    const __hip_bfloat16* pwf, const __hip_bfloat16* w0f,
    const __hip_bfloat16* w1f, const __hip_bfloat16* w2f,
    const __hip_bfloat16* obuf, float* out)
{
    constexpr int SA = 264;
    constexpr int SO = 136;
    constexpr int SH = 72;
    __shared__ __hip_bfloat16 bufA[32 * SA];   // 16.9 KB
    __shared__ __hip_bfloat16 bufB[32 * SA];   // 16.9 KB
    __shared__ __hip_bfloat16 bufH[16 * SH];   // 2.3 KB
    __shared__ float xvs[16];

    const int tid  = threadIdx.x;
    const int wv   = tid >> 6, lane = tid & 63;
    const int lx   = lane & 15, quad = lane >> 4;
    const int p0   = blockIdx.x * 16;
    const float tval = t[0];

    auto ldA = [&](const __hip_bfloat16* buf, int stride, int m0, int k0) -> s8v {
        return *(const s8v*)(buf + (m0 + lx) * stride + k0 + quad * 8);
    };
    auto ldBf = [&](const __hip_bfloat16* wf, int NT, int kt, int nt) -> s8v {
        return *(const s8v*)(wf + (((size_t)(kt * NT + nt) * 64 + lane) << 3));
    };

    // stage obuf rows (16 x 128) -> bufA stride SO
    for (int idx = tid; idx < 256; idx += 256) {
        const int row = idx >> 4, ch = idx & 15;
        *(f4v*)(bufA + row * SO + ch * 8) = *(const f4v*)(obuf + (size_t)(p0 + row) * kH + ch * 8);
    }
    if (tid < 16) xvs[tid] = x[p0 + tid];
    __syncthreads();

    {   // hfeat: M=16, N=64, K=128. wave -> N-tile wv. read bufA -> write bufH
        f4v acc0 = {};
        #pragma unroll
        for (int ktile = 0; ktile < 4; ++ktile) {
            s8v b  = ldBf(pwf, 4, ktile, wv);
            s8v a0 = ldA(bufA, SO, 0, ktile * 32);
            acc0 = MFMA(a0, b, acc0);
        }
        const int n = wv * 16 + lx;
        const float bb = p_b[n];
        #pragma unroll
        for (int r = 0; r < 4; ++r)
            bufH[(quad * 4 + r) * SH + n] = f2b(acc0[r] + bb);
    }
    __syncthreads();

    {   // L0: M=16, N=256, K=64. read bufH -> write bufB (z rows 0-15, zd rows 16-31)
        f4v acc[4] = {};
        #pragma unroll
        for (int ktile = 0; ktile < 2; ++ktile) {
            s8v a0 = ldA(bufH, SH, 0, ktile * 32);
            #pragma unroll
            for (int j = 0; j < 4; ++j) {
                s8v b = ldBf(w0f, 16, ktile, wv * 4 + j);
                acc[j] = MFMA(a0, b, acc[j]);
            }
        }
        #pragma unroll
        for (int j = 0; j < 4; ++j) {
            const int n = (wv * 4 + j) * 16 + lx;
            const float base = d_b0[n] + tval * d_w0[n];
            const float wx   = d_w0[256 + n];
            #pragma unroll
            for (int r = 0; r < 4; ++r) {
                const int m = quad * 4 + r;
                const float z = tanh_fast(acc[j][r] + base + xvs[m] * wx);
                bufB[m * SA + n]        = f2b(z);
                bufB[(m + 16) * SA + n] = f2b((1.f - z * z) * wx);
            }
        }
    }
    __syncthreads();

    {   // L1: M=32 (16 fwd + 16 tgt), N=256, K=256. read bufB -> write bufA
        f4v acc[4][2] = {};
        #pragma unroll
        for (int ktile = 0; ktile < 8; ++ktile) {
            s8v a0 = ldA(bufB, SA, 0,  ktile * 32);
            s8v a1 = ldA(bufB, SA, 16, ktile * 32);
            #pragma unroll
            for (int j = 0; j < 4; ++j) {
                s8v b = ldBf(w1f, 16, ktile, wv * 4 + j);
                acc[j][0] = MFMA(a0, b, acc[j][0]);
                acc[j][1] = MFMA(a1, b, acc[j][1]);
            }
        }
        #pragma unroll
        for (int j = 0; j < 4; ++j) {
            const int n = (wv * 4 + j) * 16 + lx;
            const float b1 = d_b1[n];
            #pragma unroll
            for (int r = 0; r < 4; ++r) {
                const int m = quad * 4 + r;
                const float z  = tanh_fast(acc[j][0][r] + b1);
                const float zd = (1.f - z * z) * acc[j][1][r];
                bufA[m * SA + n]        = f2b(z);
                bufA[(m + 16) * SA + n] = f2b(zd);
            }
        }
    }
    __syncthreads();

    {   // L2: M=32, N=128, K=256. read bufA -> write bufB (stride SO)
        f4v acc[2][2] = {};
        #pragma unroll
        for (int ktile = 0; ktile < 8; ++ktile) {
            s8v a0 = ldA(bufA, SA, 0,  ktile * 32);
            s8v a1 = ldA(bufA, SA, 16, ktile * 32);
            #pragma unroll
            for (int j = 0; j < 2; ++j) {
                s8v b = ldBf(w2f, 8, ktile, wv * 2 + j);
                acc[j][0] = MFMA(a0, b, acc[j][0]);
                acc[j][1] = MFMA(a1, b, acc[j][1]);
            }
        }
        #pragma unroll
        for (int j = 0; j < 2; ++j) {
            const int n = (wv * 2 + j) * 16 + lx;
            const float b2 = d_b2[n];
            #pragma unroll
            for (int r = 0; r < 4; ++r) {
                const int m = quad * 4 + r;
                const float z  = tanh_fast(acc[j][0][r] + b2);
                const float zd = (1.f - z * z) * acc[j][1][r];
                bufB[m * SO + n]        = f2b(z);
                bufB[(m + 16) * SO + n] = f2b(zd);
            }
        }
    }
    __syncthreads();

    {   // L3 reduce: 16 points x 16 threads, 8 cols each
        const int p = tid >> 4, s = tid & 15;
        float yv = 0.f, jv = 0.f;
        #pragma unroll
        for (int i = 0; i < 8; ++i) {
            const int n = s + i * 16;
            const float w = d_w3[n];
            yv += b2f(bufB[p * SO + n]) * w;
            jv += b2f(bufB[(p + 16) * SO + n]) * w;
        }
        #pragma unroll
        for (int off = 8; off > 0; off >>= 1) {
            yv += __shfl_down(yv, off, 16);
            jv += __shfl_down(jv, off, 16);
        }
        if (s == 0) {
            out[p0 + p]      = yv + d_b3[0];
            out[kP + p0 + p] = jv;
        }
    }
}

extern "C" void kernel_launch(void* const* d_in, const int* in_sizes, int n_in,
                              void* d_out, int out_size, void* d_ws, size_t ws_size,
                              hipStream_t stream)
{
    typedef const float* fp;
    fp t    = (fp)d_in[0];
    fp x    = (fp)d_in[1];
    fp q_w0 = (fp)d_in[2],  q_b0 = (fp)d_in[3];
    fp k_w0 = (fp)d_in[4],  k_b0 = (fp)d_in[5];
    fp v_w0 = (fp)d_in[6],  v_b0 = (fp)d_in[7];
    fp q_w1 = (fp)d_in[8],  q_b1 = (fp)d_in[9];
    fp k_w1 = (fp)d_in[10], k_b1 = (fp)d_in[11];
    fp v_w1 = (fp)d_in[12], v_b1 = (fp)d_in[13];
    fp q_w2 = (fp)d_in[14], q_b2 = (fp)d_in[15];
    fp k_w2 = (fp)d_in[16], k_b2 = (fp)d_in[17];
    fp v_w2 = (fp)d_in[18], v_b2 = (fp)d_in[19];
    fp p_w  = (fp)d_in[20], p_b  = (fp)d_in[21];
    fp d_w0 = (fp)d_in[22], d_b0 = (fp)d_in[23];
    fp d_w1 = (fp)d_in[24], d_b1 = (fp)d_in[25];
    fp d_w2 = (fp)d_in[26], d_b2 = (fp)d_in[27];
    fp d_w3 = (fp)d_in[28], d_b3 = (fp)d_in[29];

    __hip_bfloat16* wsb  = (__hip_bfloat16*)d_ws;
    __hip_bfloat16* kbuf = wsb;                                  // 2048*128
    __hip_bfloat16* vbuf = kbuf + (size_t)kBN * kH;              // 2048*128
    __hip_bfloat16* qbuf = vbuf + (size_t)kBN * kH;              // 2048*2048
    __hip_bfloat16* obuf = qbuf + (size_t)kBN * kD * kH;         // 32768*128
    __hip_bfloat16* pwf  = obuf + (size_t)kP * kH;               // 8192
    __hip_bfloat16* w0f  = pwf + 8192;                           // 16384
    __hip_bfloat16* w1f  = w0f + 16384;                          // 65536
    __hip_bfloat16* w2f  = w1f + 65536;                          // 32768
    __hip_bfloat16* k0f  = w2f + 32768;                          // 8192
    __hip_bfloat16* v0f  = k0f + 8192;                           // 8192
    __hip_bfloat16* q0f  = v0f + 8192;                           // 8192
    __hip_bfloat16* k1f  = q0f + 8192;                           // 65536
    __hip_bfloat16* v1f  = k1f + 65536;                          // 65536
    __hip_bfloat16* q1f  = v1f + 65536;                          // 65536
    __hip_bfloat16* k2f  = q1f + 65536;                          // 32768
    __hip_bfloat16* v2f  = k2f + 32768;                          // 32768
    __hip_bfloat16* q2f  = v2f + 32768;                          // 524288
    __hip_bfloat16* h1q  = q2f + 524288;                         // 2048*256

    float* out = (float*)d_out;

    prep_frag<<<456, 256, 0, stream>>>(p_w, d_w0, d_w1, d_w2,
        k_w0, k_w1, k_w2, v_w0, v_w1, v_w2, q_w0, q_w1, q_w2,
        pwf, w0f, w1f, w2f, k0f, k1f, k2f, v0f, v1f, v2f, q0f, q1f, q2f);
    mlp_kernel<<<192, 256, 0, stream>>>(x,
        k_b0, k_b1, k_b2, v_b0, v_b1, v_b2, q_b0, q_b1,
        k0f, k1f, k2f, v0f, v1f, v2f, q0f, q1f, kbuf, vbuf, h1q);
    qgemm_kernel<<<(kBN / 32) * 8, 256, 0, stream>>>(q_b2, h1q, q2f, qbuf);
    attn_kernel<<<kB * kD * 4, 256, 0, stream>>>(qbuf, kbuf, vbuf, obuf);
    dim_kernel<<<kP / 16, 256, 0, stream>>>(t, x, p_b, d_w0, d_b0, d_b1, d_b2, d_w3, d_b3,
        pwf, w0f, w1f, w2f, obuf, out);
}